// Round 8
// baseline (18402.910 us; speedup 1.0000x reference)
//
#include <hip/hip_runtime.h>
#include <cmath>

// Problem dims (fixed by reference)
#define B_   128
#define T_   500
#define MEL_ 80
#define RED_ 2
#define D_   256   // decoder dim
#define E_   128   // encoder/prenet-out dim
#define PRE_ 256   // prenet hidden
#define L_   256   // encoder length
#define TPB  1024
#define ENC_C 256  // ushorts per enc row (512B exactly; XOR-swizzled 16B chunks)
#define PTT  10    // timesteps per pre-pass block (500 % 10 == 0)

__device__ __forceinline__ float sigmoidf_(float x) { return 1.f / (1.f + expf(-x)); }
__device__ __forceinline__ float bflo(unsigned u) { return __uint_as_float(u << 16); }
__device__ __forceinline__ float bfhi(unsigned u) { return __uint_as_float(u & 0xFFFF0000u); }
__device__ __forceinline__ float bfval(ushort v) { return __uint_as_float(((unsigned)v) << 16); }
__device__ __forceinline__ ushort f2bf(float f) {
    unsigned u = __float_as_uint(f);
    return (ushort)((u + 0x7FFFu + ((u >> 16) & 1u)) >> 16);
}

// accumulate 8 bf16 (one uint4) against 8 fp32
__device__ __forceinline__ float acc8(uint4 u, const float* vv, float s) {
    s = fmaf(bflo(u.x), vv[0], s);
    s = fmaf(bfhi(u.x), vv[1], s);
    s = fmaf(bflo(u.y), vv[2], s);
    s = fmaf(bfhi(u.y), vv[3], s);
    s = fmaf(bflo(u.z), vv[4], s);
    s = fmaf(bfhi(u.z), vv[5], s);
    s = fmaf(bflo(u.w), vv[6], s);
    s = fmaf(bfhi(u.w), vv[7], s);
    return s;
}

// ---- Row-pair packed weights (PQ layout) ----
// Task t covers output rows {2*rp, 2*rp+1} and one K-part of PS*8 columns,
// where rp = t / nparts, part = t % nparts, nparts = K/(8*PS).
// Chunk c (of 2*PS): row = 2*rp + (c&1), col-chunk = part*PS + (c>>1).
// Storage: uint4 index (t>>6)*(2*PS*64) + c*64 + (t&63)  -> every wave load is
// 1KB fully contiguous; v operand (PS*8 floats) is SHARED by both rows:
// halves LDS v-reads and address VALU per weight byte vs single-row tasks.
template<int PS>
__device__ __forceinline__ float2 dotpq(const ushort* __restrict__ wp, int t, const float* v) {
    const uint4* w = reinterpret_cast<const uint4*>(wp) + (t >> 6) * (2 * PS * 64) + (t & 63);
    float e0 = 0.f, e1 = 0.f, o0 = 0.f, o1 = 0.f;
#pragma unroll 4
    for (int k = 0; k < PS; ++k) {
        uint4 we = w[(2 * k) * 64];
        uint4 wo = w[(2 * k + 1) * 64];
        const float* vv = v + k * 8;
        if (k & 1) { e1 = acc8(we, vv, e1); o1 = acc8(wo, vv, o1); }
        else       { e0 = acc8(we, vv, e0); o0 = acc8(wo, vv, o0); }
    }
    return make_float2(e0 + e1, o0 + o1);
}

// single-row packed dot (proj2 only; r4 layout)
template<int CH>
__device__ __forceinline__ float dotpk(const ushort* __restrict__ wp, int t, const float* v) {
    const uint4* w = reinterpret_cast<const uint4*>(wp) + (t >> 6) * (CH * 64) + (t & 63);
    float s0 = 0.f, s1 = 0.f, s2 = 0.f, s3 = 0.f;
#pragma unroll 2
    for (int c = 0; c < (CH & ~3); c += 4) {
        uint4 u0 = w[(c + 0) * 64];
        uint4 u1 = w[(c + 1) * 64];
        uint4 u2 = w[(c + 2) * 64];
        uint4 u3 = w[(c + 3) * 64];
        s0 = acc8(u0, v + (c + 0) * 8, s0);
        s1 = acc8(u1, v + (c + 1) * 8, s1);
        s2 = acc8(u2, v + (c + 2) * 8, s2);
        s3 = acc8(u3, v + (c + 3) * 8, s3);
    }
    return (s0 + s1) + (s2 + s3);
}

// fp32 -> PQ-packed bf16
__global__ void pack_pq_kernel(const float* __restrict__ src,
                               ushort* __restrict__ dst,
                               int R, int K, int PS) {
    int i = blockIdx.x * blockDim.x + threadIdx.x;
    int n = R * K;
    if (i >= n) return;
    int e = i & 7;
    int j = i >> 3;
    int CH = 2 * PS;
    int g = j / (CH * 64);
    int rem = j - g * (CH * 64);
    int c = rem >> 6;
    int lane = rem & 63;
    int t = g * 64 + lane;
    int nparts = K / (8 * PS);
    int rp = t / nparts;
    int part = t - rp * nparts;
    int row = 2 * rp + (c & 1);
    int colc = part * PS + (c >> 1);
    dst[i] = f2bf(src[row * K + colc * 8 + e]);
}

// fp32 -> single-row wave-group packed bf16 (proj2)
__global__ void pack_bf16_kernel(const float* __restrict__ src,
                                 ushort* __restrict__ dst,
                                 int NT, int CH, int dA, int mA, int mB) {
    int i = blockIdx.x * blockDim.x + threadIdx.x;
    int n = NT * CH * 8;
    if (i >= n) return;
    int i4 = i >> 3, e = i & 7;
    int lane = i4 & 63;
    int q = i4 >> 6;
    int c = q % CH;
    int g = q / CH;
    int t = g * 64 + lane;
    dst[i] = f2bf(src[(t / dA) * mA + (t % dA) * mB + c * 8 + e]);
}

// -------- Pre-pass: prenet + attention-GRU input gates (verified r3/r4) -----
__global__ __launch_bounds__(256) void prenet_gi_kernel(
    const float* __restrict__ dec_input,
    const float* __restrict__ pre_w1, const float* __restrict__ pre_b1,
    const float* __restrict__ pre_w2, const float* __restrict__ pre_b2,
    const float* __restrict__ attn_wih, const float* __restrict__ attn_bih,
    ushort* __restrict__ gi_out,   // chunk-local [nb, T, 3*D] bf16
    int b0)
{
    const int blk = blockIdx.x;
    const int bl  = blk / (T_ / PTT);
    const int b   = b0 + bl;
    const int t0  = (blk % (T_ / PTT)) * PTT;
    const int tid = threadIdx.x;

    __shared__ float fr[PTT][MEL_];
    __shared__ float x1[PTT][PRE_];
    __shared__ float x2[PTT][E_];

    for (int i = tid; i < PTT * MEL_; i += 256) {
        int f = i / MEL_, m = i - f * MEL_;
        fr[f][m] = dec_input[((size_t)b * T_ + t0 + f) * MEL_ + m];
    }
    __syncthreads();

    {
        float acc[PTT];
#pragma unroll
        for (int f = 0; f < PTT; ++f) acc[f] = pre_b1[tid];
        const float4* wr = reinterpret_cast<const float4*>(pre_w1 + tid * MEL_);
        for (int k4 = 0; k4 < MEL_ / 4; ++k4) {
            float4 w = wr[k4];
#pragma unroll
            for (int f = 0; f < PTT; ++f) {
                const float* fp = &fr[f][k4 * 4];
                acc[f] = fmaf(w.x, fp[0], fmaf(w.y, fp[1], fmaf(w.z, fp[2], fmaf(w.w, fp[3], acc[f]))));
            }
        }
#pragma unroll
        for (int f = 0; f < PTT; ++f) x1[f][tid] = fmaxf(acc[f], 0.f);
    }
    __syncthreads();

    if (tid < E_) {
        float acc[PTT];
#pragma unroll
        for (int f = 0; f < PTT; ++f) acc[f] = pre_b2[tid];
        const float4* wr = reinterpret_cast<const float4*>(pre_w2 + tid * PRE_);
        for (int k4 = 0; k4 < PRE_ / 4; ++k4) {
            float4 w = wr[k4];
#pragma unroll
            for (int f = 0; f < PTT; ++f) {
                const float* fp = &x1[f][k4 * 4];
                acc[f] = fmaf(w.x, fp[0], fmaf(w.y, fp[1], fmaf(w.z, fp[2], fmaf(w.w, fp[3], acc[f]))));
            }
        }
#pragma unroll
        for (int f = 0; f < PTT; ++f) x2[f][tid] = fmaxf(acc[f], 0.f);
    }
    __syncthreads();

    for (int r = tid; r < 3 * D_; r += 256) {
        float acc[PTT];
#pragma unroll
        for (int f = 0; f < PTT; ++f) acc[f] = attn_bih[r];
        const float4* wr = reinterpret_cast<const float4*>(attn_wih + r * E_);
        for (int k4 = 0; k4 < E_ / 4; ++k4) {
            float4 w = wr[k4];
#pragma unroll
            for (int f = 0; f < PTT; ++f) {
                const float* fp = &x2[f][k4 * 4];
                acc[f] = fmaf(w.x, fp[0], fmaf(w.y, fp[1], fmaf(w.z, fp[2], fmaf(w.w, fp[3], acc[f]))));
            }
        }
#pragma unroll
        for (int f = 0; f < PTT; ++f)
            gi_out[((size_t)bl * T_ + t0 + f) * (3 * D_) + r] = f2bf(acc[f]);
    }
}

// Persistent decoder (r4 structure) with row-pair PQ tasks everywhere.
// Merged gh phase: 3072 tasks exactly (attn quarter-pairs 1536 + rnn half-pairs
// 1536) -> 3 tasks/thread. Same weight bytes as r4; half the LDS v-reads.
__global__ __launch_bounds__(TPB, 4) void decoder_persist(
    const float* __restrict__ enc_output,  // [B,L,D] fp32
    const ushort* __restrict__ attn_whh, const float* __restrict__ attn_bhh,
    const ushort* __restrict__ proj1_w, const float* __restrict__ proj1_b,
    const ushort* __restrict__ rnn1_wih, const ushort* __restrict__ rnn1_whh,
    const float* __restrict__ rnn1_bih, const float* __restrict__ rnn1_bhh,
    const ushort* __restrict__ rnn2_wih, const ushort* __restrict__ rnn2_whh,
    const float* __restrict__ rnn2_bih, const float* __restrict__ rnn2_bhh,
    const ushort* __restrict__ proj2_w, const float* __restrict__ proj2_b,
    const ushort* __restrict__ gi_g,       // chunk-local [nb,T,3*D] bf16
    int b0,
    float* __restrict__ mel_out,   // [B, T*RED, MEL]
    float* __restrict__ align_out) // [B, L, T]
{
    const int tid  = threadIdx.x;
    const int lane = tid & 63;
    const int wv   = tid >> 6;
    const int bl   = blockIdx.x;
    const int b    = b0 + bl;

    // LDS ~159 KB -> 1 block/CU
    __shared__ __align__(16) ushort s_enc[L_ * ENC_C];   // 131072 B
    __shared__ __align__(16) float A[3072];   // scratch partials (attn-gh/scores/ctx/proj1/wih/proj2)
    __shared__ __align__(16) float G[3072];   // rnn1-gh [0,1536) + rnn2-gh [1536,3072), layout [row*2+half]
    __shared__ __align__(16) float s_ha[D_];
    __shared__ __align__(16) float s_h1[D_];
    __shared__ __align__(16) float s_h2[D_];
    __shared__ __align__(16) float s_dec[D_];
    __shared__ __align__(16) float s_y1[D_];  // ctx before proj1, then y1
    __shared__ __align__(16) float s_y2[D_];
    __shared__ __align__(16) float s_al[L_];
    __shared__ float s_pmax[4];
    __shared__ float s_psum[4];

    // ---- stage enc[b] fp32 -> bf16 LDS, XOR-swizzled 16B chunks ----
    // chunk c of row r stored at slot (c&24) | ((c&7)^(r&7))
    {
        const float4* eb = reinterpret_cast<const float4*>(enc_output + (size_t)b * L_ * D_);
        for (int i = tid; i < (L_ * D_) / 4; i += TPB) {
            float4 f = eb[i];
            int row = i >> 6;
            int c4  = i & 63;
            int c    = c4 >> 1;
            int half = c4 & 1;
            int slot = (c & 24) | ((c & 7) ^ (row & 7));
            uint2 pk;
            pk.x = (unsigned)f2bf(f.x) | ((unsigned)f2bf(f.y) << 16);
            pk.y = (unsigned)f2bf(f.z) | ((unsigned)f2bf(f.w) << 16);
            *reinterpret_cast<uint2*>(s_enc + row * ENC_C + slot * 8 + half * 4) = pk;
        }
    }
    if (tid < D_) { s_ha[tid] = 0.f; s_h1[tid] = 0.f; s_h2[tid] = 0.f; }
    __syncthreads();

    for (int t = 0; t < T_; ++t) {
        // [A] merged gh: 3072 pair-tasks, exactly 3/thread.
        //  tasks [0,1536): attn quarter-pairs (PS=8) -> A[row*4+q]
        //  tasks [1536,3072): rnn half-pairs (PS=16) -> G[row*2+half]
        for (int task = tid; task < 3072; task += TPB) {
            if (task < 1536) {
                int q = task & 3, rp = task >> 2;
                float2 r = dotpq<8>(attn_whh, task, s_ha + q * 64);
                A[(2 * rp) * 4 + q]     = r.x;
                A[(2 * rp + 1) * 4 + q] = r.y;
            } else {
                int u = task - 1536;
                const ushort* wm; const float* h; float* Gb;
                if (u < 768) { wm = rnn1_whh; h = s_h1; Gb = G; }
                else         { u -= 768; wm = rnn2_whh; h = s_h2; Gb = G + 1536; }
                int half = u & 1, rp = u >> 1;
                float2 r = dotpq<16>(wm, u, h + half * 128);
                Gb[(2 * rp) * 2 + half]     = r.x;
                Gb[(2 * rp + 1) * 2 + half] = r.y;
            }
        }
        __syncthreads();

        // [B] attn GRU combine (gi from pre-pass; gh = 4 quarter partials)
        if (tid < D_) {
            const ushort* gp = gi_g + ((size_t)bl * T_ + t) * (3 * D_);
            float gir = bfval(gp[tid]);
            float giz = bfval(gp[D_ + tid]);
            float gin = bfval(gp[2 * D_ + tid]);
            int r0 = tid * 4, r1 = (D_ + tid) * 4, r2 = (2 * D_ + tid) * 4;
            float ghr = ((A[r0] + A[r0 + 1]) + (A[r0 + 2] + A[r0 + 3])) + attn_bhh[tid];
            float ghz = ((A[r1] + A[r1 + 1]) + (A[r1 + 2] + A[r1 + 3])) + attn_bhh[D_ + tid];
            float ghn = ((A[r2] + A[r2 + 1]) + (A[r2 + 2] + A[r2 + 3])) + attn_bhh[2 * D_ + tid];
            float r = sigmoidf_(gir + ghr);
            float z = sigmoidf_(giz + ghz);
            float n = tanhf(gin + r * ghn);
            s_ha[tid] = (1.f - z) * n + z * s_ha[tid];
        }
        __syncthreads();

        // [C] scores: 256 rows x 4-way K-split; swizzle-aware b128 reads
        {
            int p = tid >> 8, l = tid & 255;
            const uint4* rowp = reinterpret_cast<const uint4*>(s_enc + l * ENC_C) + p * 8;
            const float* v = s_ha + p * 64;
            int rot = l & 7;
            float a0 = 0.f, a1 = 0.f, a2 = 0.f, a3 = 0.f;
#pragma unroll
            for (int k = 0; k < 8; k += 4) {
                uint4 u0 = rowp[(k + 0) ^ rot];
                uint4 u1 = rowp[(k + 1) ^ rot];
                uint4 u2 = rowp[(k + 2) ^ rot];
                uint4 u3 = rowp[(k + 3) ^ rot];
                a0 = acc8(u0, v + (k + 0) * 8, a0);
                a1 = acc8(u1, v + (k + 1) * 8, a1);
                a2 = acc8(u2, v + (k + 2) * 8, a2);
                a3 = acc8(u3, v + (k + 3) * 8, a3);
            }
            A[p * 256 + l] = (a0 + a1) + (a2 + a3);
        }
        __syncthreads();
        float sc = 0.f, e = 0.f;
        // [D] finalize score + block max
        if (tid < L_) {
            sc = A[tid] + A[256 + tid] + A[512 + tid] + A[768 + tid];
            float m = sc;
            for (int o = 32; o > 0; o >>= 1) m = fmaxf(m, __shfl_xor(m, o, 64));
            if (lane == 0) s_pmax[wv] = m;
        }
        __syncthreads();
        // [E] exp + block sum
        if (tid < L_) {
            float mm = fmaxf(fmaxf(s_pmax[0], s_pmax[1]), fmaxf(s_pmax[2], s_pmax[3]));
            e = expf(sc - mm);
            float sm = e;
            for (int o = 32; o > 0; o >>= 1) sm += __shfl_xor(sm, o, 64);
            if (lane == 0) s_psum[wv] = sm;
        }
        __syncthreads();
        // [F] alignment
        if (tid < L_) {
            float denom = s_psum[0] + s_psum[1] + s_psum[2] + s_psum[3];
            float al = e / denom;
            s_al[tid] = al;
            align_out[((size_t)b * L_ + tid) * T_ + t] = al;
        }
        __syncthreads();

        // [G] ctx partials: 256 cols x 4-way L-split (swizzle-aware)
        {
            int p = tid >> 8, d = tid & 255;
            int chigh = (d >> 3) & 24, clow = (d >> 3) & 7, el = d & 7;
            const float* alp = s_al + p * 64;
            float a0 = 0.f, a1 = 0.f;
            for (int l8 = 0; l8 < 8; ++l8) {
                const ushort* rb = s_enc + (p * 64 + l8 * 8) * ENC_C;
                const float* al8 = alp + l8 * 8;
#pragma unroll
                for (int dr = 0; dr < 8; ++dr) {
                    int slot = chigh | (clow ^ dr);
                    float vv = bfval(rb[dr * ENC_C + slot * 8 + el]);
                    if (dr & 1) a1 = fmaf(al8[dr], vv, a1);
                    else        a0 = fmaf(al8[dr], vv, a0);
                }
            }
            A[p * 256 + d] = a0 + a1;
        }
        __syncthreads();
        // [H] ctx combine -> s_y1
        if (tid < D_)
            s_y1[tid] = A[tid] + A[256 + tid] + A[512 + tid] + A[768 + tid];
        __syncthreads();

        // [I] proj1: eighth-pairs (PS=8, K=512), 1024 tasks, 1/thread.
        // cat = [ctx(s_y1), ha]; part p covers cols p*64.
        {
            int part = tid & 7, rp = tid >> 3;
            const float* v = (part < 4) ? (s_y1 + part * 64) : (s_ha + (part - 4) * 64);
            float2 r = dotpq<8>(proj1_w, tid, v);
            A[(2 * rp) * 8 + part]     = r.x;
            A[(2 * rp + 1) * 8 + part] = r.y;
        }
        __syncthreads();
        // [J] proj1 combine (8 part partials)
        if (tid < D_) {
            float s = proj1_b[tid];
#pragma unroll
            for (int p = 0; p < 8; ++p) s += A[tid * 8 + p];
            s_dec[tid] = s;
        }
        __syncthreads();

        // [K] rnn1 wih: quarter-pairs, 1536 tasks
        for (int task = tid; task < 1536; task += TPB) {
            int q = task & 3, rp = task >> 2;
            float2 r = dotpq<8>(rnn1_wih, task, s_dec + q * 64);
            A[(2 * rp) * 4 + q]     = r.x;
            A[(2 * rp + 1) * 4 + q] = r.y;
        }
        __syncthreads();
        // [L] rnn1 combine (gi = 4 quarters from A; gh = 2 halves from G)
        if (tid < D_) {
            int r0 = tid * 4, r1 = (D_ + tid) * 4, r2 = (2 * D_ + tid) * 4;
            float gir = ((A[r0] + A[r0 + 1]) + (A[r0 + 2] + A[r0 + 3])) + rnn1_bih[tid];
            float giz = ((A[r1] + A[r1 + 1]) + (A[r1 + 2] + A[r1 + 3])) + rnn1_bih[D_ + tid];
            float gin = ((A[r2] + A[r2 + 1]) + (A[r2 + 2] + A[r2 + 3])) + rnn1_bih[2 * D_ + tid];
            float ghr = G[2 * tid] + G[2 * tid + 1] + rnn1_bhh[tid];
            float ghz = G[2 * (D_ + tid)] + G[2 * (D_ + tid) + 1] + rnn1_bhh[D_ + tid];
            float ghn = G[2 * (2 * D_ + tid)] + G[2 * (2 * D_ + tid) + 1] + rnn1_bhh[2 * D_ + tid];
            float r = sigmoidf_(gir + ghr);
            float z = sigmoidf_(giz + ghz);
            float n = tanhf(gin + r * ghn);
            float hn = (1.f - z) * n + z * s_h1[tid];
            s_h1[tid] = hn;
            s_y1[tid] = s_dec[tid] + hn;
        }
        __syncthreads();

        // [M] rnn2 wih: quarter-pairs, 1536 tasks
        for (int task = tid; task < 1536; task += TPB) {
            int q = task & 3, rp = task >> 2;
            float2 r = dotpq<8>(rnn2_wih, task, s_y1 + q * 64);
            A[(2 * rp) * 4 + q]     = r.x;
            A[(2 * rp + 1) * 4 + q] = r.y;
        }
        __syncthreads();
        // [N] rnn2 combine (gh from G[1536..3072))
        if (tid < D_) {
            const float* Gb = G + 1536;
            int r0 = tid * 4, r1 = (D_ + tid) * 4, r2 = (2 * D_ + tid) * 4;
            float gir = ((A[r0] + A[r0 + 1]) + (A[r0 + 2] + A[r0 + 3])) + rnn2_bih[tid];
            float giz = ((A[r1] + A[r1 + 1]) + (A[r1 + 2] + A[r1 + 3])) + rnn2_bih[D_ + tid];
            float gin = ((A[r2] + A[r2 + 1]) + (A[r2 + 2] + A[r2 + 3])) + rnn2_bih[2 * D_ + tid];
            float ghr = Gb[2 * tid] + Gb[2 * tid + 1] + rnn2_bhh[tid];
            float ghz = Gb[2 * (D_ + tid)] + Gb[2 * (D_ + tid) + 1] + rnn2_bhh[D_ + tid];
            float ghn = Gb[2 * (2 * D_ + tid)] + Gb[2 * (2 * D_ + tid) + 1] + rnn2_bhh[2 * D_ + tid];
            float r = sigmoidf_(gir + ghr);
            float z = sigmoidf_(giz + ghz);
            float n = tanhf(gin + r * ghn);
            float hn = (1.f - z) * n + z * s_h2[tid];
            s_h2[tid] = hn;
            s_y2[tid] = s_y1[tid] + hn;
        }
        __syncthreads();

        // [O] proj2 partials: 640 single-row tasks (r4 layout), K split 4-way
        if (tid < 640)
            A[tid] = dotpk<8>(proj2_w, tid, s_y2 + (tid & 3) * 64);
        __syncthreads();
        // [P] proj2 combine + mel store
        if (tid < MEL_ * RED_) {
            float s = A[4 * tid] + A[4 * tid + 1] + A[4 * tid + 2] + A[4 * tid + 3] + proj2_b[tid];
            mel_out[(size_t)b * (T_ * RED_ * MEL_) + (size_t)t * (MEL_ * RED_) + tid] = s;
        }
        __syncthreads();   // A rewritten at next step's [A]
    }
}

extern "C" void kernel_launch(void* const* d_in, const int* in_sizes, int n_in,
                              void* d_out, int out_size, void* d_ws, size_t ws_size,
                              hipStream_t stream) {
    const float* dec_input = (const float*)d_in[0];
    const float* enc_output= (const float*)d_in[1];
    const float* pre_w1    = (const float*)d_in[2];
    const float* pre_b1    = (const float*)d_in[3];
    const float* pre_w2    = (const float*)d_in[4];
    const float* pre_b2    = (const float*)d_in[5];
    const float* attn_wih  = (const float*)d_in[6];
    const float* attn_whh  = (const float*)d_in[7];
    const float* attn_bih  = (const float*)d_in[8];
    const float* attn_bhh  = (const float*)d_in[9];
    const float* proj1_w   = (const float*)d_in[10];
    const float* proj1_b   = (const float*)d_in[11];
    const float* rnn1_wih  = (const float*)d_in[12];
    const float* rnn1_whh  = (const float*)d_in[13];
    const float* rnn1_bih  = (const float*)d_in[14];
    const float* rnn1_bhh  = (const float*)d_in[15];
    const float* rnn2_wih  = (const float*)d_in[16];
    const float* rnn2_whh  = (const float*)d_in[17];
    const float* rnn2_bih  = (const float*)d_in[18];
    const float* rnn2_bhh  = (const float*)d_in[19];
    const float* proj2_w   = (const float*)d_in[20];
    const float* proj2_b   = (const float*)d_in[21];

    float* mel   = (float*)d_out;
    float* align = (float*)d_out + (size_t)B_ * T_ * RED_ * MEL_;

    // bf16 packed weight scratch (element counts)
    const int n_whh   = 3 * D_ * D_;        // 196608
    const int n_proj1 = D_ * 2 * D_;        // 131072
    const int n_proj2 = MEL_ * RED_ * D_;   // 40960

    ushort* w = (ushort*)d_ws;
    ushort* c_attn_whh = w; w += n_whh;
    ushort* c_proj1    = w; w += n_proj1;
    ushort* c_rnn1_wih = w; w += n_whh;
    ushort* c_rnn1_whh = w; w += n_whh;
    ushort* c_rnn2_wih = w; w += n_whh;
    ushort* c_rnn2_whh = w; w += n_whh;
    ushort* c_proj2    = w; w += n_proj2;
    ushort* c_gi       = w;   // gi chunk buffer starts here

    auto packpq = [&](const float* src, ushort* dst, int R, int K, int PS) {
        int n = R * K;
        pack_pq_kernel<<<dim3((n + 255) / 256), dim3(256), 0, stream>>>(src, dst, R, K, PS);
    };
    packpq(attn_whh, c_attn_whh, 768, 256, 8);    // quarter-pairs
    packpq(rnn1_whh, c_rnn1_whh, 768, 256, 16);   // half-pairs
    packpq(rnn2_whh, c_rnn2_whh, 768, 256, 16);
    packpq(rnn1_wih, c_rnn1_wih, 768, 256, 8);
    packpq(rnn2_wih, c_rnn2_wih, 768, 256, 8);
    packpq(proj1_w,  c_proj1,    256, 512, 8);    // eighth-pairs
    {
        int n = 640 * 8 * 8;
        pack_bf16_kernel<<<dim3((n + 255) / 256), dim3(256), 0, stream>>>(
            proj2_w, c_proj2, 640, 8, 4, 256, 64);
    }

    // gi chunking by available workspace (observed harness ws fits all 128)
    const size_t gi_per_b = (size_t)T_ * 3 * D_;          // elems per batch
    size_t used = (size_t)((char*)c_gi - (char*)d_ws);
    size_t avail = (ws_size > used) ? (ws_size - used) : 0;
    int bchunk = (int)(avail / (gi_per_b * sizeof(ushort)));
    if (bchunk > B_) bchunk = B_;
    if (bchunk < 1)  bchunk = 1;

    for (int b0 = 0; b0 < B_; b0 += bchunk) {
        int nb = (b0 + bchunk <= B_) ? bchunk : (B_ - b0);
        prenet_gi_kernel<<<dim3(nb * (T_ / PTT)), dim3(256), 0, stream>>>(
            dec_input, pre_w1, pre_b1, pre_w2, pre_b2, attn_wih, attn_bih,
            c_gi, b0);
        decoder_persist<<<dim3(nb), dim3(TPB), 0, stream>>>(
            enc_output,
            c_attn_whh, attn_bhh,
            c_proj1, proj1_b,
            c_rnn1_wih, c_rnn1_whh, rnn1_bih, rnn1_bhh,
            c_rnn2_wih, c_rnn2_whh, rnn2_bih, rnn2_bhh,
            c_proj2, proj2_b,
            c_gi, b0,
            mel, align);
    }
}